// Round 14
// baseline (229.704 us; speedup 1.0000x reference)
//
#include <hip/hip_runtime.h>
#include <math.h>

typedef unsigned short u16;
typedef __attribute__((ext_vector_type(8))) _Float16 half8;
typedef __attribute__((ext_vector_type(4))) float f32x4;
typedef __attribute__((ext_vector_type(4))) unsigned short us4;

// r30: tscan prefix-scan WIN -> 204.4us best.
// r31: parallel-replica probe CONFOUNDED (cache sharing + overlap): marginal
//      21.1us for 3x concurrent prep+chunk_t copies — lower bound only.
// r32: SERIAL probe. prep and chunk_t bodies wrapped in a 4x serial rep loop
//      per block (barrier + memory clobber between reps; identical writes).
//      Serial reps can't overlap => each dispatch ~= P + 3*P_warm, surfaces
//      in top-5 WITH counters if fat. dur = 204.4 + 3(Pw+Cw).
//      Branch: both rows visible + dur>290 -> fix prep/chunk_t per signature;
//      dur<250 -> they're thin, fat is QKVG -> 8-phase port next.

static __device__ __forceinline__ u16 f2h(float f) {
    _Float16 h = (_Float16)f;
    return __builtin_bit_cast(u16, h);
}
static __device__ __forceinline__ float h2f(u16 u) {
    return (float)__builtin_bit_cast(_Float16, u);
}
static __device__ __forceinline__ void gl_lds16(const void* g, void* l) {
    __builtin_amdgcn_global_load_lds(
        (const __attribute__((address_space(1))) void*)g,
        (__attribute__((address_space(3))) void*)l, 16, 0, 0);
}

// ---------- prep: weight transpose + embed-LN.  r32: 4x SERIAL rep ----------
__global__ __launch_bounds__(256) void prep_kernel(
    const float* __restrict__ Wq, const float* __restrict__ Wk, const float* __restrict__ Wv,
    const float* __restrict__ Wg, const float* __restrict__ Wo, const float* __restrict__ W1,
    const float* __restrict__ W2, u16* __restrict__ WT,
    const int* __restrict__ ids, const float* __restrict__ emb, const float* __restrict__ pos,
    const float* __restrict__ gam, const float* __restrict__ bet, u16* __restrict__ x0h)
{
    __shared__ float tile[64][65];
    int bx = blockIdx.x, t = threadIdx.x;
    for (int rep = 0; rep < 4; ++rep) {
    if (bx < 448) {
        const float* Ws[7] = {Wq, Wk, Wv, Wg, Wo, W1, W2};
        int w = bx >> 6, rem = bx & 63;
        int k0 = (rem >> 3) * 64, n0 = (rem & 7) * 64;
        const float* W = Ws[w];
        for (int c = t; c < 4096; c += 256) {
            int row = c >> 6, col = c & 63;
            tile[row][col] = W[(size_t)(k0 + row) * 512 + n0 + col];
        }
        __syncthreads();
        for (int c = t; c < 4096; c += 256) {
            int row = c >> 6, col = c & 63;
            WT[(size_t)w * 262144 + (size_t)(n0 + row) * 512 + k0 + col] = f2h(tile[col][row]);
        }
    } else {
        int wid = t >> 6, lane = t & 63;
        int rbase = (bx - 448) * 8 + wid * 2;
        int col = lane * 8;
        int id0 = ids[2 * 8192 + rbase];
        int id1 = ids[2 * 8192 + rbase + 1];
        const float* pp0 = pos + (size_t)(2 * 1024 + (rbase & 1023)) * 512 + col;
        const float* pp1 = pos + (size_t)(2 * 1024 + ((rbase + 1) & 1023)) * 512 + col;
        float4 pa0 = *(const float4*)pp0, pa1 = *(const float4*)(pp0 + 4);
        float4 pb0 = *(const float4*)pp1, pb1 = *(const float4*)(pp1 + 4);
        float4 g0 = *(const float4*)&gam[col], g1 = *(const float4*)&gam[col + 4];
        float4 c0 = *(const float4*)&bet[col], c1 = *(const float4*)&bet[col + 4];
        const float* ep0 = emb + (size_t)(2 * 1024 + id0) * 512 + col;
        const float* ep1 = emb + (size_t)(2 * 1024 + id1) * 512 + col;
        float4 ea0 = *(const float4*)ep0, ea1 = *(const float4*)(ep0 + 4);
        float4 eb0 = *(const float4*)ep1, eb1 = *(const float4*)(ep1 + 4);

        float va[8] = {ea0.x + pa0.x, ea0.y + pa0.y, ea0.z + pa0.z, ea0.w + pa0.w,
                       ea1.x + pa1.x, ea1.y + pa1.y, ea1.z + pa1.z, ea1.w + pa1.w};
        float vb[8] = {eb0.x + pb0.x, eb0.y + pb0.y, eb0.z + pb0.z, eb0.w + pb0.w,
                       eb1.x + pb1.x, eb1.y + pb1.y, eb1.z + pb1.z, eb1.w + pb1.w};
        float s1a = 0.f, s2a = 0.f, s1b = 0.f, s2b = 0.f;
#pragma unroll
        for (int j = 0; j < 8; ++j) {
            s1a += va[j]; s2a += va[j] * va[j];
            s1b += vb[j]; s2b += vb[j] * vb[j];
        }
#pragma unroll
        for (int o = 32; o >= 1; o >>= 1) {
            s1a += __shfl_xor(s1a, o, 64);
            s2a += __shfl_xor(s2a, o, 64);
            s1b += __shfl_xor(s1b, o, 64);
            s2b += __shfl_xor(s2b, o, 64);
        }
        float mua = s1a * (1.f / 512.f);
        float vara = fmaxf(s2a * (1.f / 512.f) - mua * mua, 0.f);
        float rsa = 1.f / sqrtf(vara + 1e-5f);
        float mub = s1b * (1.f / 512.f);
        float varb = fmaxf(s2b * (1.f / 512.f) - mub * mub, 0.f);
        float rsb = 1.f / sqrtf(varb + 1e-5f);
        float gv[8] = {g0.x, g0.y, g0.z, g0.w, g1.x, g1.y, g1.z, g1.w};
        float bv[8] = {c0.x, c0.y, c0.z, c0.w, c1.x, c1.y, c1.z, c1.w};
        half8 ha, hb;
#pragma unroll
        for (int j = 0; j < 8; ++j) {
            ha[j] = (_Float16)((va[j] - mua) * rsa * gv[j] + bv[j]);
            hb[j] = (_Float16)((vb[j] - mub) * rsb * gv[j] + bv[j]);
        }
        *(half8*)&x0h[(size_t)rbase * 512 + col] = ha;
        *(half8*)&x0h[(size_t)(rbase + 1) * 512 + col] = hb;
    }
    __syncthreads();
    asm volatile("" ::: "memory");   // r32: force re-execution per rep (no CSE)
    }
}

// ---------- LayerNorm, row-per-wave; optional fused FC partial ----------
__global__ __launch_bounds__(256) void ln_kernel(
    const u16* __restrict__ xin,
    const float* __restrict__ gam, const float* __restrict__ bet,
    u16* __restrict__ outh,
    const float* __restrict__ fcW, float* __restrict__ fcpart)
{
    int wid = threadIdx.x >> 6, lane = threadIdx.x & 63;
    int row = blockIdx.x * 4 + wid;
    int col = lane * 8;
    float v[8];
    half8 x = *(const half8*)&xin[(size_t)row * 512 + col];
#pragma unroll
    for (int j = 0; j < 8; ++j) v[j] = (float)x[j];
    float s1 = 0.f, s2 = 0.f;
#pragma unroll
    for (int j = 0; j < 8; ++j) { s1 += v[j]; s2 += v[j] * v[j]; }
#pragma unroll
    for (int o = 32; o >= 1; o >>= 1) {
        s1 += __shfl_xor(s1, o, 64);
        s2 += __shfl_xor(s2, o, 64);
    }
    float mu = s1 * (1.f / 512.f);
    float var = fmaxf(s2 * (1.f / 512.f) - mu * mu, 0.f);
    float rs = 1.f / sqrtf(var + 1e-5f);
    float4 g0 = *(const float4*)&gam[col], g1 = *(const float4*)&gam[col + 4];
    float4 b0 = *(const float4*)&bet[col], b1 = *(const float4*)&bet[col + 4];
    float gv[8] = {g0.x, g0.y, g0.z, g0.w, g1.x, g1.y, g1.z, g1.w};
    float bv[8] = {b0.x, b0.y, b0.z, b0.w, b1.x, b1.y, b1.z, b1.w};
    float y[8];
#pragma unroll
    for (int j = 0; j < 8; ++j) y[j] = (v[j] - mu) * rs * gv[j] + bv[j];
    if (outh) {
        half8 hv;
#pragma unroll
        for (int j = 0; j < 8; ++j) hv[j] = (_Float16)y[j];
        *(half8*)&outh[(size_t)row * 512 + col] = hv;
    }
    if (fcW) {
        int srow = row & 1023;
        const float* wp = &fcW[(size_t)srow * 512 + col];
        float4 w0 = *(const float4*)wp, w1 = *(const float4*)(wp + 4);
        float d = y[0] * w0.x + y[1] * w0.y + y[2] * w0.z + y[3] * w0.w +
                  y[4] * w1.x + y[5] * w1.y + y[6] * w1.z + y[7] * w1.w;
#pragma unroll
        for (int o = 32; o >= 1; o >>= 1) d += __shfl_xor(d, o, 64);
        if (lane == 0) fcpart[row] = d;
    }
}

// ---------- QKVG GEMM: 256x256 tile, 8 waves, BK=32, quad-buffer counted-vmcnt ----------
static __device__ __forceinline__ void stage_tile(
    const u16* pa0, const u16* pa1, const u16* pb0, const u16* pb1,
    u16* ldsw, int slot, int kt)
{
    int off = kt * 32;
    u16* d = ldsw + slot * 16384;
    gl_lds16(pa0 + off, d);
    gl_lds16(pa1 + off, d + 4096);
    gl_lds16(pb0 + off, d + 8192);
    gl_lds16(pb1 + off, d + 12288);
}

static __device__ __forceinline__ void compute_tile(
    const u16* lds, int slot, int wm, int wn, int quad, int l15, f32x4 (&acc)[8][4])
{
    const u16* A = lds + slot * 16384;
    const u16* B = A + 8192;
    __builtin_amdgcn_s_setprio(1);
#pragma unroll
    for (int mq = 0; mq < 2; ++mq)
#pragma unroll
        for (int nq = 0; nq < 2; ++nq) {
            half8 a[4], b[2];
#pragma unroll
            for (int i = 0; i < 4; ++i)
                a[i] = *(const half8*)&A[(wm * 128 + mq * 64 + i * 16 + l15) * 32 + quad * 8];
#pragma unroll
            for (int j = 0; j < 2; ++j)
                b[j] = *(const half8*)&B[(wn * 64 + nq * 32 + j * 16 + l15) * 32 + quad * 8];
#pragma unroll
            for (int i = 0; i < 4; ++i)
#pragma unroll
                for (int j = 0; j < 2; ++j)
                    acc[mq * 4 + i][nq * 2 + j] = __builtin_amdgcn_mfma_f32_16x16x32_f16(
                        a[i], b[j], acc[mq * 4 + i][nq * 2 + j], 0, 0, 0);
        }
    __builtin_amdgcn_s_setprio(0);
}

#define QITER(KT, VM)                                                              \
    do {                                                                           \
        if ((KT) + 3 < 16) stage_tile(pa0, pa1, pb0, pb1, ldsw, ((KT) + 3) & 3, (KT) + 3); \
        asm volatile("s_waitcnt vmcnt(" #VM ")" ::: "memory");                     \
        __builtin_amdgcn_s_barrier();                                              \
        asm volatile("" ::: "memory");                                             \
        compute_tile(lds, (KT) & 3, wm, wn, quad, l15, acc);                       \
        asm volatile("" ::: "memory");                                             \
        __builtin_amdgcn_s_barrier();                                              \
    } while (0)

__global__ __launch_bounds__(512, 2) void gemm_f16(
    const u16* __restrict__ A2, const u16* __restrict__ Bg,
    u16* __restrict__ outh, int ostride)
{
    __shared__ u16 lds[65536];
    int t = threadIdx.x;
    int wid = t >> 6, lane = t & 63, quad = lane >> 4, l15 = lane & 15;
    int wm = wid >> 2, wn = wid & 3;
    int orig = blockIdx.x;
    int wgid = (orig & 7) * 32 + (orig >> 3);
    int m0 = (wgid >> 3) * 256, n0 = (wgid & 7) * 256;

    int srow = t >> 2, sc = (t & 3) * 8;
    const u16* pa0 = A2 + (size_t)(m0 + srow) * 512 + sc;
    const u16* pa1 = pa0 + (size_t)128 * 512;
    const u16* pb0 = Bg + (size_t)(n0 + srow) * 512 + sc;
    const u16* pb1 = pb0 + (size_t)128 * 512;
    u16* ldsw = lds + wid * 512;

    f32x4 acc[8][4];
#pragma unroll
    for (int i = 0; i < 8; ++i)
#pragma unroll
        for (int j = 0; j < 4; ++j) acc[i][j] = (f32x4){0.f, 0.f, 0.f, 0.f};

    stage_tile(pa0, pa1, pb0, pb1, ldsw, 0, 0);
    stage_tile(pa0, pa1, pb0, pb1, ldsw, 1, 1);
    stage_tile(pa0, pa1, pb0, pb1, ldsw, 2, 2);

    QITER(0, 12);  QITER(1, 12);  QITER(2, 12);  QITER(3, 12);
    QITER(4, 12);  QITER(5, 12);  QITER(6, 12);  QITER(7, 12);
    QITER(8, 12);  QITER(9, 12);  QITER(10, 12); QITER(11, 12);
    QITER(12, 12);
    QITER(13, 8);  QITER(14, 4);  QITER(15, 0);

    u16* C = lds;
#pragma unroll
    for (int i = 0; i < 8; ++i)
#pragma unroll
        for (int j = 0; j < 4; ++j)
#pragma unroll
            for (int r = 0; r < 4; ++r)
                C[(wm * 128 + i * 16 + quad * 4 + r) * 256 + wn * 64 + j * 16 + l15] =
                    f2h(acc[i][j][r]);
    __builtin_amdgcn_s_barrier();
    asm volatile("" ::: "memory");
#pragma unroll
    for (int it = 0; it < 16; ++it) {
        int idx = it * 512 + t;
        int row = idx >> 5, ch = idx & 31;
        *(half8*)&outh[(size_t)(m0 + row) * ostride + n0 + ch * 8] =
            *(const half8*)&C[row * 256 + ch * 8];
    }
}

// ---------- GEMM N=512 layers: 128x128 tile, 8 waves, BK=32, counted-vmcnt ----------
// mode 1: C+res16 ; 2: relu(C+bias) ; 3: C+bias+res16
static __device__ __forceinline__ void stage_n64(
    const u16* pa, const u16* pb, u16* ldsw, int slot, int kt)
{
    int off = kt * 32;
    u16* d = ldsw + slot * 8192;
    gl_lds16(pa + off, d);
    gl_lds16(pb + off, d + 4096);
}

static __device__ __forceinline__ void compute_n64(
    const u16* lds, int slot, int wm, int wn, int quad, int l15, f32x4 (&acc)[4][2])
{
    const u16* A = lds + slot * 8192;
    const u16* B = A + 4096;
    __builtin_amdgcn_s_setprio(1);
    half8 a[4], b[2];
#pragma unroll
    for (int i = 0; i < 4; ++i)
        a[i] = *(const half8*)&A[(wm * 64 + i * 16 + l15) * 32 + quad * 8];
#pragma unroll
    for (int j = 0; j < 2; ++j)
        b[j] = *(const half8*)&B[(wn * 32 + j * 16 + l15) * 32 + quad * 8];
#pragma unroll
    for (int i = 0; i < 4; ++i)
#pragma unroll
        for (int j = 0; j < 2; ++j)
            acc[i][j] = __builtin_amdgcn_mfma_f32_16x16x32_f16(a[i], b[j], acc[i][j], 0, 0, 0);
    __builtin_amdgcn_s_setprio(0);
}

#define NITER(KT, VM)                                                          \
    do {                                                                       \
        if ((KT) + 3 < 16) stage_n64(pa, pb, ldsw, ((KT) + 3) & 3, (KT) + 3);  \
        asm volatile("s_waitcnt vmcnt(" #VM ")" ::: "memory");                 \
        __builtin_amdgcn_s_barrier();                                          \
        asm volatile("" ::: "memory");                                         \
        compute_n64(lds, (KT) & 3, wm, wn, quad, l15, acc);                    \
        asm volatile("" ::: "memory");                                         \
        __builtin_amdgcn_s_barrier();                                          \
    } while (0)

__global__ __launch_bounds__(512, 2) void gemm_f16_n64(
    const u16* __restrict__ A2, const u16* __restrict__ Bg,
    u16* __restrict__ outh,
    const u16* __restrict__ res, const float* __restrict__ bias, int mode)
{
    __shared__ u16 lds[32768];
    int t = threadIdx.x;
    int wid = t >> 6, lane = t & 63, quad = lane >> 4, l15 = lane & 15;
    int wm = wid >> 2, wn = wid & 3;
    int orig = blockIdx.x;
    int wgid = (orig & 7) * 32 + (orig >> 3);
    int m0 = (wgid >> 2) * 128, n0 = (wgid & 3) * 128;

    int srow = t >> 2, sc = (t & 3) * 8;
    const u16* pa = A2 + (size_t)(m0 + srow) * 512 + sc;
    const u16* pb = Bg + (size_t)(n0 + srow) * 512 + sc;
    u16* ldsw = lds + wid * 512;

    f32x4 acc[4][2];
#pragma unroll
    for (int i = 0; i < 4; ++i)
#pragma unroll
        for (int j = 0; j < 2; ++j) acc[i][j] = (f32x4){0.f, 0.f, 0.f, 0.f};

    stage_n64(pa, pb, ldsw, 0, 0);
    stage_n64(pa, pb, ldsw, 1, 1);
    stage_n64(pa, pb, ldsw, 2, 2);

    NITER(0, 6);  NITER(1, 6);  NITER(2, 6);  NITER(3, 6);
    NITER(4, 6);  NITER(5, 6);  NITER(6, 6);  NITER(7, 6);
    NITER(8, 6);  NITER(9, 6);  NITER(10, 6); NITER(11, 6);
    NITER(12, 6);
    NITER(13, 4); NITER(14, 2); NITER(15, 0);

#pragma unroll
    for (int i = 0; i < 4; ++i)
#pragma unroll
        for (int j = 0; j < 2; ++j) {
            int nl = wn * 32 + j * 16 + l15;
            int n = n0 + nl;
#pragma unroll
            for (int r = 0; r < 4; ++r) {
                int rl = wm * 64 + i * 16 + quad * 4 + r;
                int m = m0 + rl;
                float v = acc[i][j][r];
                if (mode == 1) v += h2f(res[(size_t)m * 512 + n]);
                else if (mode == 2) v = fmaxf(v + bias[n], 0.f);
                else if (mode == 3) v += bias[n] + h2f(res[(size_t)m * 512 + n]);
                lds[rl * 128 + nl] = f2h(v);
            }
        }
    __builtin_amdgcn_s_barrier();
    asm volatile("" ::: "memory");
#pragma unroll
    for (int it = 0; it < 4; ++it) {
        int idx = it * 512 + t;
        int row = idx >> 4, ch = idx & 15;
        *(half8*)&outh[(size_t)(m0 + row) * 512 + n0 + ch * 8] =
            *(const half8*)&lds[row * 128 + ch * 8];
    }
}

// ---------- chunk T.  r32: 4x SERIAL rep ----------
__global__ __launch_bounds__(256) void chunk_t(
    const u16* __restrict__ QKVGh, u16* __restrict__ Tst)
{
    __shared__ u16 kth[64 * 144];
    __shared__ u16 vth[64 * 144];
    int t = threadIdx.x;
    int wid = t >> 6, lane = t & 63, quad = lane >> 4, l15 = lane & 15;
    int bh = blockIdx.x >> 3, c = blockIdx.x & 7;
    int b = bh >> 3, h = bh & 7;
    float gamma = 1.f - exp2f(-(float)(5 + h));
    float l2g = log2f(gamma);

    for (int rep = 0; rep < 4; ++rep) {
    for (int cc = t; cc < 2048; cc += 256) {
        int d = cc & 63, mseg = cc >> 6;
        size_t gbase = (size_t)(b * 1024 + c * 128 + mseg * 4) * 2048 + h * 64 + d;
        us4 k4, v4;
#pragma unroll
        for (int i = 0; i < 4; ++i) {
            float kv = h2f(QKVGh[gbase + 512 + (size_t)i * 2048]);
            k4[i] = f2h(kv * exp2f((float)(127 - (mseg * 4 + i)) * l2g));
            v4[i] = QKVGh[gbase + 1024 + (size_t)i * 2048];
        }
        int base = d * 144 + (((mseg >> 1) + d) & 15) * 8 + (mseg & 1) * 4;
        *(us4*)&kth[base] = k4;
        *(us4*)&vth[base] = v4;
    }
    __syncthreads();
    f32x4 T[4];
#pragma unroll
    for (int dt = 0; dt < 4; ++dt) T[dt] = (f32x4){0.f, 0.f, 0.f, 0.f};
    int ra = wid * 16 + l15;
#pragma unroll
    for (int ks = 0; ks < 4; ++ks) {
        half8 av = *(const half8*)&vth[ra * 144 + ((ks * 4 + quad + ra) & 15) * 8];
#pragma unroll
        for (int dt = 0; dt < 4; ++dt) {
            int rb = dt * 16 + l15;
            half8 bk = *(const half8*)&kth[rb * 144 + ((ks * 4 + quad + rb) & 15) * 8];
            T[dt] = __builtin_amdgcn_mfma_f32_16x16x32_f16(av, bk, T[dt], 0, 0, 0);
        }
    }
#pragma unroll
    for (int dt = 0; dt < 4; ++dt)
#pragma unroll
        for (int r = 0; r < 4; ++r) {
            int i = wid * 16 + quad * 4 + r;
            int j = dt * 16 + l15;
            Tst[(((size_t)bh * 8 + c) * 64 + i) * 64 + j] = f2h(T[dt][r]);
        }
    __syncthreads();
    asm volatile("" ::: "memory");   // r32: force re-execution per rep
    }
}

// ---------- tscan: per-(bh) prefix scan over chunk T's ----------
__global__ __launch_bounds__(256) void tscan(
    const u16* __restrict__ Tst, u16* __restrict__ Sst)
{
    int bh = blockIdx.x >> 3, p = blockIdx.x & 7;
    int h = bh & 7;
    float gamma = 1.f - exp2f(-(float)(5 + h));
    float g128 = exp2f(128.f * log2f(gamma));
    int e = p * 512 + threadIdx.x * 2;
    const u16* tp = Tst + (size_t)bh * 32768 + e;
    u16* sp = Sst + (size_t)bh * 32768 + e;
    float s0 = 0.f, s1 = 0.f;
#pragma unroll
    for (int c = 0; c < 8; ++c) {
        sp[c * 4096] = f2h(s0);
        sp[c * 4096 + 1] = f2h(s1);
        s0 = g128 * s0 + h2f(tp[c * 4096]);
        s1 = g128 * s1 + h2f(tp[c * 4096 + 1]);
    }
}

// ---------- retention: prefix from Sst ----------
__global__ __launch_bounds__(256) void retention_f16(
    const u16* __restrict__ QKVGh, const u16* __restrict__ Sst, u16* __restrict__ Zh)
{
    __shared__ u16 kh[128 * 64];
    __shared__ u16 vth[64 * 144];
    __shared__ u16 ph[4][16 * 132];

    int t = threadIdx.x;
    int wid = t >> 6, lane = t & 63, quad = lane >> 4, l15 = lane & 15;
    int bh = blockIdx.x >> 3, qt = blockIdx.x & 7;
    int b = bh >> 3, h = bh & 7;
    int n0 = qt * 128;

    float gamma = 1.f - exp2f(-(float)(5 + h));
    float l2g = log2f(gamma);

    {
        int srow = wid * 8 + (lane >> 3);
        int scol = (lane & 7) * 8;
#pragma unroll
        for (int i = 0; i < 4; ++i) {
            int r = i * 32 + srow;
            gl_lds16(&QKVGh[(size_t)(b * 1024 + n0 + r) * 2048 + 512 + h * 64 + scol],
                     &kh[(i * 32 + wid * 8) * 64]);
        }
    }
    for (int c = t; c < 2048; c += 256) {
        int d = c & 63, mseg = c >> 6;
        size_t gbase = (size_t)(b * 1024 + n0 + mseg * 4) * 2048 + 1024 + h * 64 + d;
        us4 v4 = {QKVGh[gbase], QKVGh[gbase + 2048],
                  QKVGh[gbase + 4096], QKVGh[gbase + 6144]};
        int base = d * 144 + (((mseg >> 1) + d) & 15) * 8 + (mseg & 1) * 4;
        *(us4*)&vth[base] = v4;
    }

    half8 aH[2][2], aHs[2][2];
#pragma unroll
    for (int g = 0; g < 2; ++g) {
        int rowloc = wid * 32 + g * 16 + l15;
        int qrow = b * 1024 + n0 + rowloc;
        const u16* qp = QKVGh + (size_t)qrow * 2048 + h * 64;
        float qs = exp2f((float)(rowloc + 1) * l2g - 3.f);
#pragma unroll
        for (int ks = 0; ks < 2; ++ks) {
            aH[g][ks] = *(const half8*)&qp[ks * 32 + quad * 8];
#pragma unroll
            for (int j = 0; j < 8; ++j)
                aHs[g][ks][j] = (_Float16)((float)aH[g][ks][j] * qs);
        }
    }

    half8 sf[2][4];
    {
        const u16* sp = &Sst[((size_t)bh * 8 + qt) * 4096];
#pragma unroll
        for (int ks = 0; ks < 2; ++ks)
#pragma unroll
            for (int dt = 0; dt < 4; ++dt)
                sf[ks][dt] = *(const half8*)&sp[(dt * 16 + l15) * 64 + ks * 32 + quad * 8];
    }
    __syncthreads();

    f32x4 yacc[2][4];
#pragma unroll
    for (int g = 0; g < 2; ++g)
#pragma unroll
        for (int dt = 0; dt < 4; ++dt) yacc[g][dt] = (f32x4){0.f, 0.f, 0.f, 0.f};

#pragma unroll
    for (int ks = 0; ks < 2; ++ks)
#pragma unroll
        for (int g = 0; g < 2; ++g)
#pragma unroll
            for (int dt = 0; dt < 4; ++dt)
                yacc[g][dt] = __builtin_amdgcn_mfma_f32_16x16x32_f16(aHs[g][ks], sf[ks][dt], yacc[g][dt], 0, 0, 0);

#pragma unroll
    for (int g = 0; g < 2; ++g) {
        f32x4 sacc[8];
#pragma unroll
        for (int tn = 0; tn < 8; ++tn) sacc[tn] = (f32x4){0.f, 0.f, 0.f, 0.f};
#pragma unroll
        for (int tn = 0; tn < 8; ++tn)
#pragma unroll
            for (int ks = 0; ks < 2; ++ks) {
                half8 bH = *(const half8*)&kh[(tn * 16 + l15) * 64 + ks * 32 + quad * 8];
                sacc[tn] = __builtin_amdgcn_mfma_f32_16x16x32_f16(aH[g][ks], bH, sacc[tn], 0, 0, 0);
            }
#pragma unroll
        for (int tn = 0; tn < 8; ++tn) {
            int mloc = tn * 16 + l15;
#pragma unroll
            for (int r = 0; r < 4; ++r) {
                int nloc = wid * 32 + g * 16 + quad * 4 + r;
                int diff = nloc - mloc;
                float p = (diff >= 0) ? sacc[tn][r] * exp2f((float)diff * l2g - 3.0f) : 0.f;
                ph[wid][(quad * 4 + r) * 132 + tn * 16 + l15] = f2h(p);
            }
        }
        half8 pH[4];
#pragma unroll
        for (int ks = 0; ks < 4; ++ks)
            pH[ks] = *(const half8*)&ph[wid][l15 * 132 + ks * 32 + quad * 8];
#pragma unroll
        for (int dt = 0; dt < 4; ++dt) {
            int d = dt * 16 + l15;
#pragma unroll
            for (int ks = 0; ks < 4; ++ks) {
                half8 vv = *(const half8*)&vth[d * 144 + ((ks * 4 + quad + d) & 15) * 8];
                yacc[g][dt] = __builtin_amdgcn_mfma_f32_16x16x32_f16(pH[ks], vv, yacc[g][dt], 0, 0, 0);
            }
        }
    }

#pragma unroll
    for (int g = 0; g < 2; ++g) {
#pragma unroll
        for (int r = 0; r < 4; ++r) {
            float s1 = yacc[g][0][r] + yacc[g][1][r] + yacc[g][2][r] + yacc[g][3][r];
            float s2 = yacc[g][0][r] * yacc[g][0][r] + yacc[g][1][r] * yacc[g][1][r] +
                       yacc[g][2][r] * yacc[g][2][r] + yacc[g][3][r] * yacc[g][3][r];
#pragma unroll
            for (int o = 1; o <= 8; o <<= 1) {
                s1 += __shfl_xor(s1, o, 64);
                s2 += __shfl_xor(s2, o, 64);
            }
            float mu = s1 * (1.f / 64.f);
            float var = fmaxf(s2 * (1.f / 64.f) - mu * mu, 0.f);
            float rs = 1.f / sqrtf(var + 1e-5f);
            int nglob = n0 + wid * 32 + g * 16 + quad * 4 + r;
            size_t grow = (size_t)(b * 1024 + nglob);
#pragma unroll
            for (int dt = 0; dt < 4; ++dt) {
                int d = dt * 16 + l15;
                float yv = (yacc[g][dt][r] - mu) * rs;
                float gt = h2f(QKVGh[grow * 2048 + 1536 + h * 64 + d]);
                float sw = gt / (1.f + expf(-gt));
                Zh[grow * 512 + h * 64 + d] = f2h(yv * sw);
            }
        }
    }
}

// ---------- final reduce ----------
__global__ __launch_bounds__(256) void fc_final(const float* __restrict__ fcpart,
                                                const float* __restrict__ fcb,
                                                float* __restrict__ out)
{
    __shared__ float red[4];
    int b = blockIdx.x, t = threadIdx.x;
    float4 v = *(const float4*)&fcpart[(size_t)b * 1024 + t * 4];
    float s = v.x + v.y + v.z + v.w;
    int wid = t >> 6, lane = t & 63;
#pragma unroll
    for (int o = 32; o >= 1; o >>= 1) s += __shfl_xor(s, o, 64);
    if (lane == 0) red[wid] = s;
    __syncthreads();
    if (t == 0) {
        float l = red[0] + red[1] + red[2] + red[3] + fcb[0];
        out[b] = 1.f / (1.f + expf(-l));
    }
}

extern "C" void kernel_launch(void* const* d_in, const int* in_sizes, int n_in,
                              void* d_out, int out_size, void* d_ws, size_t ws_size,
                              hipStream_t stream)
{
    const int* ids = (const int*)d_in[0];
    const float* emb = (const float*)d_in[1];
    const float* pos = (const float*)d_in[2];
    const float* ln_g = (const float*)d_in[3];
    const float* ln_b = (const float*)d_in[4];
    const float* Wq = (const float*)d_in[5];
    const float* Wk = (const float*)d_in[6];
    const float* Wv = (const float*)d_in[7];
    const float* Wg = (const float*)d_in[8];
    const float* Wo = (const float*)d_in[9];
    const float* W1 = (const float*)d_in[10];
    const float* b1 = (const float*)d_in[11];
    const float* W2 = (const float*)d_in[12];
    const float* b2 = (const float*)d_in[13];
    const float* fcW = (const float*)d_in[14];
    const float* fcb = (const float*)d_in[15];
    float* out = (float*)d_out;

    char* ws = (char*)d_ws;
    u16* WT     = (u16*)(ws);                  //  3,670,016
    u16* x0h    = (u16*)(ws + 3670016);        //  8,388,608  LN(emb) f16 (A + residual)
    u16* Zh     = (u16*)(ws + 12058624);       //  8,388,608  retention out f16
    u16* QKVGh  = (u16*)(ws + 20447232);       // 33,554,432  [8192][2048] f16
    float* fcpart = (float*)(ws + 54001664);   // 32,768
    u16* Tst    = (u16*)(ws + 54034432);       //  4,194,304  per-chunk T
    u16* Sst    = (u16*)(ws + 58228736);       //  4,194,304  prefix states
    u16* X1h = QKVGh;
    u16* Th  = (u16*)((char*)QKVGh + 8388608);
    u16* Hh  = (u16*)((char*)QKVGh + 16777216);
    u16* X2h = Zh;

    prep_kernel<<<1472, 256, 0, stream>>>(Wq, Wk, Wv, Wg, Wo, W1, W2, WT,
                                          ids, emb, pos, ln_g, ln_b, x0h);
    gemm_f16<<<256, 512, 0, stream>>>(x0h, WT, QKVGh, 2048);
    chunk_t<<<512, 256, 0, stream>>>(QKVGh, Tst);
    tscan<<<512, 256, 0, stream>>>(Tst, Sst);
    retention_f16<<<512, 256, 0, stream>>>(QKVGh, Sst, Zh);
    gemm_f16_n64<<<256, 512, 0, stream>>>(Zh, WT + 4 * 262144, X1h, x0h, nullptr, 1);
    ln_kernel<<<2048, 256, 0, stream>>>(X1h, ln_g, ln_b, Th, nullptr, nullptr);
    gemm_f16_n64<<<256, 512, 0, stream>>>(Th, WT + 5 * 262144, Hh, nullptr, b1, 2);
    gemm_f16_n64<<<256, 512, 0, stream>>>(Hh, WT + 6 * 262144, X2h, X1h, b2, 3);
    ln_kernel<<<2048, 256, 0, stream>>>(X2h, ln_g, ln_b, nullptr, fcW, fcpart);
    fc_final<<<8, 256, 0, stream>>>(fcpart, fcb, out);
}

// Round 15
// 199.781 us; speedup vs baseline: 1.1498x; 1.1498x over previous
//
#include <hip/hip_runtime.h>
#include <math.h>

typedef unsigned short u16;
typedef __attribute__((ext_vector_type(8))) _Float16 half8;
typedef __attribute__((ext_vector_type(4))) float f32x4;
typedef __attribute__((ext_vector_type(4))) unsigned short us4;

// r30: tscan prefix-scan WIN -> 204.4us best.
// r31/r32: probes. r32 MEASURED: prep+chunk_t warm ~8.4us TOTAL (thin);
//      retention surfaced with counters: ~47-50us, MfmaUtil 1.8%, VALU 15%,
//      HBM 6.6%, Occ 20.8% -> pure latency-bound, 8 waves/CU too few.
// r33: retention g-loop -> wave parallelism. 512 thr / 8 waves per block,
//      wave wid owns q-rows wid*16+l15 (old (wid,g) <-> new wid*2+g; all
//      per-element math + reduce order bit-identical). Serial chain /2,
//      waves/CU 8 -> 16 (LDS 68.6KB, 2 blocks/CU). Probes removed.

static __device__ __forceinline__ u16 f2h(float f) {
    _Float16 h = (_Float16)f;
    return __builtin_bit_cast(u16, h);
}
static __device__ __forceinline__ float h2f(u16 u) {
    return (float)__builtin_bit_cast(_Float16, u);
}
static __device__ __forceinline__ void gl_lds16(const void* g, void* l) {
    __builtin_amdgcn_global_load_lds(
        (const __attribute__((address_space(1))) void*)g,
        (__attribute__((address_space(3))) void*)l, 16, 0, 0);
}

// ---------- prep: weight transpose (448 blocks) + embed-LN (1024 blocks, 2 rows/wave) ----------
__global__ __launch_bounds__(256) void prep_kernel(
    const float* __restrict__ Wq, const float* __restrict__ Wk, const float* __restrict__ Wv,
    const float* __restrict__ Wg, const float* __restrict__ Wo, const float* __restrict__ W1,
    const float* __restrict__ W2, u16* __restrict__ WT,
    const int* __restrict__ ids, const float* __restrict__ emb, const float* __restrict__ pos,
    const float* __restrict__ gam, const float* __restrict__ bet, u16* __restrict__ x0h)
{
    __shared__ float tile[64][65];
    int bx = blockIdx.x, t = threadIdx.x;
    if (bx < 448) {
        const float* Ws[7] = {Wq, Wk, Wv, Wg, Wo, W1, W2};
        int w = bx >> 6, rem = bx & 63;
        int k0 = (rem >> 3) * 64, n0 = (rem & 7) * 64;
        const float* W = Ws[w];
        for (int c = t; c < 4096; c += 256) {
            int row = c >> 6, col = c & 63;
            tile[row][col] = W[(size_t)(k0 + row) * 512 + n0 + col];
        }
        __syncthreads();
        for (int c = t; c < 4096; c += 256) {
            int row = c >> 6, col = c & 63;
            WT[(size_t)w * 262144 + (size_t)(n0 + row) * 512 + k0 + col] = f2h(tile[col][row]);
        }
    } else {
        int wid = t >> 6, lane = t & 63;
        int rbase = (bx - 448) * 8 + wid * 2;
        int col = lane * 8;
        int id0 = ids[2 * 8192 + rbase];
        int id1 = ids[2 * 8192 + rbase + 1];
        const float* pp0 = pos + (size_t)(2 * 1024 + (rbase & 1023)) * 512 + col;
        const float* pp1 = pos + (size_t)(2 * 1024 + ((rbase + 1) & 1023)) * 512 + col;
        float4 pa0 = *(const float4*)pp0, pa1 = *(const float4*)(pp0 + 4);
        float4 pb0 = *(const float4*)pp1, pb1 = *(const float4*)(pp1 + 4);
        float4 g0 = *(const float4*)&gam[col], g1 = *(const float4*)&gam[col + 4];
        float4 c0 = *(const float4*)&bet[col], c1 = *(const float4*)&bet[col + 4];
        const float* ep0 = emb + (size_t)(2 * 1024 + id0) * 512 + col;
        const float* ep1 = emb + (size_t)(2 * 1024 + id1) * 512 + col;
        float4 ea0 = *(const float4*)ep0, ea1 = *(const float4*)(ep0 + 4);
        float4 eb0 = *(const float4*)ep1, eb1 = *(const float4*)(ep1 + 4);

        float va[8] = {ea0.x + pa0.x, ea0.y + pa0.y, ea0.z + pa0.z, ea0.w + pa0.w,
                       ea1.x + pa1.x, ea1.y + pa1.y, ea1.z + pa1.z, ea1.w + pa1.w};
        float vb[8] = {eb0.x + pb0.x, eb0.y + pb0.y, eb0.z + pb0.z, eb0.w + pb0.w,
                       eb1.x + pb1.x, eb1.y + pb1.y, eb1.z + pb1.z, eb1.w + pb1.w};
        float s1a = 0.f, s2a = 0.f, s1b = 0.f, s2b = 0.f;
#pragma unroll
        for (int j = 0; j < 8; ++j) {
            s1a += va[j]; s2a += va[j] * va[j];
            s1b += vb[j]; s2b += vb[j] * vb[j];
        }
#pragma unroll
        for (int o = 32; o >= 1; o >>= 1) {
            s1a += __shfl_xor(s1a, o, 64);
            s2a += __shfl_xor(s2a, o, 64);
            s1b += __shfl_xor(s1b, o, 64);
            s2b += __shfl_xor(s2b, o, 64);
        }
        float mua = s1a * (1.f / 512.f);
        float vara = fmaxf(s2a * (1.f / 512.f) - mua * mua, 0.f);
        float rsa = 1.f / sqrtf(vara + 1e-5f);
        float mub = s1b * (1.f / 512.f);
        float varb = fmaxf(s2b * (1.f / 512.f) - mub * mub, 0.f);
        float rsb = 1.f / sqrtf(varb + 1e-5f);
        float gv[8] = {g0.x, g0.y, g0.z, g0.w, g1.x, g1.y, g1.z, g1.w};
        float bv[8] = {c0.x, c0.y, c0.z, c0.w, c1.x, c1.y, c1.z, c1.w};
        half8 ha, hb;
#pragma unroll
        for (int j = 0; j < 8; ++j) {
            ha[j] = (_Float16)((va[j] - mua) * rsa * gv[j] + bv[j]);
            hb[j] = (_Float16)((vb[j] - mub) * rsb * gv[j] + bv[j]);
        }
        *(half8*)&x0h[(size_t)rbase * 512 + col] = ha;
        *(half8*)&x0h[(size_t)(rbase + 1) * 512 + col] = hb;
    }
}

// ---------- LayerNorm, row-per-wave; optional fused FC partial ----------
__global__ __launch_bounds__(256) void ln_kernel(
    const u16* __restrict__ xin,
    const float* __restrict__ gam, const float* __restrict__ bet,
    u16* __restrict__ outh,
    const float* __restrict__ fcW, float* __restrict__ fcpart)
{
    int wid = threadIdx.x >> 6, lane = threadIdx.x & 63;
    int row = blockIdx.x * 4 + wid;
    int col = lane * 8;
    float v[8];
    half8 x = *(const half8*)&xin[(size_t)row * 512 + col];
#pragma unroll
    for (int j = 0; j < 8; ++j) v[j] = (float)x[j];
    float s1 = 0.f, s2 = 0.f;
#pragma unroll
    for (int j = 0; j < 8; ++j) { s1 += v[j]; s2 += v[j] * v[j]; }
#pragma unroll
    for (int o = 32; o >= 1; o >>= 1) {
        s1 += __shfl_xor(s1, o, 64);
        s2 += __shfl_xor(s2, o, 64);
    }
    float mu = s1 * (1.f / 512.f);
    float var = fmaxf(s2 * (1.f / 512.f) - mu * mu, 0.f);
    float rs = 1.f / sqrtf(var + 1e-5f);
    float4 g0 = *(const float4*)&gam[col], g1 = *(const float4*)&gam[col + 4];
    float4 b0 = *(const float4*)&bet[col], b1 = *(const float4*)&bet[col + 4];
    float gv[8] = {g0.x, g0.y, g0.z, g0.w, g1.x, g1.y, g1.z, g1.w};
    float bv[8] = {b0.x, b0.y, b0.z, b0.w, b1.x, b1.y, b1.z, b1.w};
    float y[8];
#pragma unroll
    for (int j = 0; j < 8; ++j) y[j] = (v[j] - mu) * rs * gv[j] + bv[j];
    if (outh) {
        half8 hv;
#pragma unroll
        for (int j = 0; j < 8; ++j) hv[j] = (_Float16)y[j];
        *(half8*)&outh[(size_t)row * 512 + col] = hv;
    }
    if (fcW) {
        int srow = row & 1023;
        const float* wp = &fcW[(size_t)srow * 512 + col];
        float4 w0 = *(const float4*)wp, w1 = *(const float4*)(wp + 4);
        float d = y[0] * w0.x + y[1] * w0.y + y[2] * w0.z + y[3] * w0.w +
                  y[4] * w1.x + y[5] * w1.y + y[6] * w1.z + y[7] * w1.w;
#pragma unroll
        for (int o = 32; o >= 1; o >>= 1) d += __shfl_xor(d, o, 64);
        if (lane == 0) fcpart[row] = d;
    }
}

// ---------- QKVG GEMM: 256x256 tile, 8 waves, BK=32, quad-buffer counted-vmcnt ----------
static __device__ __forceinline__ void stage_tile(
    const u16* pa0, const u16* pa1, const u16* pb0, const u16* pb1,
    u16* ldsw, int slot, int kt)
{
    int off = kt * 32;
    u16* d = ldsw + slot * 16384;
    gl_lds16(pa0 + off, d);
    gl_lds16(pa1 + off, d + 4096);
    gl_lds16(pb0 + off, d + 8192);
    gl_lds16(pb1 + off, d + 12288);
}

static __device__ __forceinline__ void compute_tile(
    const u16* lds, int slot, int wm, int wn, int quad, int l15, f32x4 (&acc)[8][4])
{
    const u16* A = lds + slot * 16384;
    const u16* B = A + 8192;
    __builtin_amdgcn_s_setprio(1);
#pragma unroll
    for (int mq = 0; mq < 2; ++mq)
#pragma unroll
        for (int nq = 0; nq < 2; ++nq) {
            half8 a[4], b[2];
#pragma unroll
            for (int i = 0; i < 4; ++i)
                a[i] = *(const half8*)&A[(wm * 128 + mq * 64 + i * 16 + l15) * 32 + quad * 8];
#pragma unroll
            for (int j = 0; j < 2; ++j)
                b[j] = *(const half8*)&B[(wn * 64 + nq * 32 + j * 16 + l15) * 32 + quad * 8];
#pragma unroll
            for (int i = 0; i < 4; ++i)
#pragma unroll
                for (int j = 0; j < 2; ++j)
                    acc[mq * 4 + i][nq * 2 + j] = __builtin_amdgcn_mfma_f32_16x16x32_f16(
                        a[i], b[j], acc[mq * 4 + i][nq * 2 + j], 0, 0, 0);
        }
    __builtin_amdgcn_s_setprio(0);
}

#define QITER(KT, VM)                                                              \
    do {                                                                           \
        if ((KT) + 3 < 16) stage_tile(pa0, pa1, pb0, pb1, ldsw, ((KT) + 3) & 3, (KT) + 3); \
        asm volatile("s_waitcnt vmcnt(" #VM ")" ::: "memory");                     \
        __builtin_amdgcn_s_barrier();                                              \
        asm volatile("" ::: "memory");                                             \
        compute_tile(lds, (KT) & 3, wm, wn, quad, l15, acc);                       \
        asm volatile("" ::: "memory");                                             \
        __builtin_amdgcn_s_barrier();                                              \
    } while (0)

__global__ __launch_bounds__(512, 2) void gemm_f16(
    const u16* __restrict__ A2, const u16* __restrict__ Bg,
    u16* __restrict__ outh, int ostride)
{
    __shared__ u16 lds[65536];
    int t = threadIdx.x;
    int wid = t >> 6, lane = t & 63, quad = lane >> 4, l15 = lane & 15;
    int wm = wid >> 2, wn = wid & 3;
    int orig = blockIdx.x;
    int wgid = (orig & 7) * 32 + (orig >> 3);
    int m0 = (wgid >> 3) * 256, n0 = (wgid & 7) * 256;

    int srow = t >> 2, sc = (t & 3) * 8;
    const u16* pa0 = A2 + (size_t)(m0 + srow) * 512 + sc;
    const u16* pa1 = pa0 + (size_t)128 * 512;
    const u16* pb0 = Bg + (size_t)(n0 + srow) * 512 + sc;
    const u16* pb1 = pb0 + (size_t)128 * 512;
    u16* ldsw = lds + wid * 512;

    f32x4 acc[8][4];
#pragma unroll
    for (int i = 0; i < 8; ++i)
#pragma unroll
        for (int j = 0; j < 4; ++j) acc[i][j] = (f32x4){0.f, 0.f, 0.f, 0.f};

    stage_tile(pa0, pa1, pb0, pb1, ldsw, 0, 0);
    stage_tile(pa0, pa1, pb0, pb1, ldsw, 1, 1);
    stage_tile(pa0, pa1, pb0, pb1, ldsw, 2, 2);

    QITER(0, 12);  QITER(1, 12);  QITER(2, 12);  QITER(3, 12);
    QITER(4, 12);  QITER(5, 12);  QITER(6, 12);  QITER(7, 12);
    QITER(8, 12);  QITER(9, 12);  QITER(10, 12); QITER(11, 12);
    QITER(12, 12);
    QITER(13, 8);  QITER(14, 4);  QITER(15, 0);

    u16* C = lds;
#pragma unroll
    for (int i = 0; i < 8; ++i)
#pragma unroll
        for (int j = 0; j < 4; ++j)
#pragma unroll
            for (int r = 0; r < 4; ++r)
                C[(wm * 128 + i * 16 + quad * 4 + r) * 256 + wn * 64 + j * 16 + l15] =
                    f2h(acc[i][j][r]);
    __builtin_amdgcn_s_barrier();
    asm volatile("" ::: "memory");
#pragma unroll
    for (int it = 0; it < 16; ++it) {
        int idx = it * 512 + t;
        int row = idx >> 5, ch = idx & 31;
        *(half8*)&outh[(size_t)(m0 + row) * ostride + n0 + ch * 8] =
            *(const half8*)&C[row * 256 + ch * 8];
    }
}

// ---------- GEMM N=512 layers: 128x128 tile, 8 waves, BK=32, counted-vmcnt ----------
// mode 1: C+res16 ; 2: relu(C+bias) ; 3: C+bias+res16
static __device__ __forceinline__ void stage_n64(
    const u16* pa, const u16* pb, u16* ldsw, int slot, int kt)
{
    int off = kt * 32;
    u16* d = ldsw + slot * 8192;
    gl_lds16(pa + off, d);
    gl_lds16(pb + off, d + 4096);
}

static __device__ __forceinline__ void compute_n64(
    const u16* lds, int slot, int wm, int wn, int quad, int l15, f32x4 (&acc)[4][2])
{
    const u16* A = lds + slot * 8192;
    const u16* B = A + 4096;
    __builtin_amdgcn_s_setprio(1);
    half8 a[4], b[2];
#pragma unroll
    for (int i = 0; i < 4; ++i)
        a[i] = *(const half8*)&A[(wm * 64 + i * 16 + l15) * 32 + quad * 8];
#pragma unroll
    for (int j = 0; j < 2; ++j)
        b[j] = *(const half8*)&B[(wn * 32 + j * 16 + l15) * 32 + quad * 8];
#pragma unroll
    for (int i = 0; i < 4; ++i)
#pragma unroll
        for (int j = 0; j < 2; ++j)
            acc[i][j] = __builtin_amdgcn_mfma_f32_16x16x32_f16(a[i], b[j], acc[i][j], 0, 0, 0);
    __builtin_amdgcn_s_setprio(0);
}

#define NITER(KT, VM)                                                          \
    do {                                                                       \
        if ((KT) + 3 < 16) stage_n64(pa, pb, ldsw, ((KT) + 3) & 3, (KT) + 3);  \
        asm volatile("s_waitcnt vmcnt(" #VM ")" ::: "memory");                 \
        __builtin_amdgcn_s_barrier();                                          \
        asm volatile("" ::: "memory");                                         \
        compute_n64(lds, (KT) & 3, wm, wn, quad, l15, acc);                    \
        asm volatile("" ::: "memory");                                         \
        __builtin_amdgcn_s_barrier();                                          \
    } while (0)

__global__ __launch_bounds__(512, 2) void gemm_f16_n64(
    const u16* __restrict__ A2, const u16* __restrict__ Bg,
    u16* __restrict__ outh,
    const u16* __restrict__ res, const float* __restrict__ bias, int mode)
{
    __shared__ u16 lds[32768];
    int t = threadIdx.x;
    int wid = t >> 6, lane = t & 63, quad = lane >> 4, l15 = lane & 15;
    int wm = wid >> 2, wn = wid & 3;
    int orig = blockIdx.x;
    int wgid = (orig & 7) * 32 + (orig >> 3);
    int m0 = (wgid >> 2) * 128, n0 = (wgid & 3) * 128;

    int srow = t >> 2, sc = (t & 3) * 8;
    const u16* pa = A2 + (size_t)(m0 + srow) * 512 + sc;
    const u16* pb = Bg + (size_t)(n0 + srow) * 512 + sc;
    u16* ldsw = lds + wid * 512;

    f32x4 acc[4][2];
#pragma unroll
    for (int i = 0; i < 4; ++i)
#pragma unroll
        for (int j = 0; j < 2; ++j) acc[i][j] = (f32x4){0.f, 0.f, 0.f, 0.f};

    stage_n64(pa, pb, ldsw, 0, 0);
    stage_n64(pa, pb, ldsw, 1, 1);
    stage_n64(pa, pb, ldsw, 2, 2);

    NITER(0, 6);  NITER(1, 6);  NITER(2, 6);  NITER(3, 6);
    NITER(4, 6);  NITER(5, 6);  NITER(6, 6);  NITER(7, 6);
    NITER(8, 6);  NITER(9, 6);  NITER(10, 6); NITER(11, 6);
    NITER(12, 6);
    NITER(13, 4); NITER(14, 2); NITER(15, 0);

#pragma unroll
    for (int i = 0; i < 4; ++i)
#pragma unroll
        for (int j = 0; j < 2; ++j) {
            int nl = wn * 32 + j * 16 + l15;
            int n = n0 + nl;
#pragma unroll
            for (int r = 0; r < 4; ++r) {
                int rl = wm * 64 + i * 16 + quad * 4 + r;
                int m = m0 + rl;
                float v = acc[i][j][r];
                if (mode == 1) v += h2f(res[(size_t)m * 512 + n]);
                else if (mode == 2) v = fmaxf(v + bias[n], 0.f);
                else if (mode == 3) v += bias[n] + h2f(res[(size_t)m * 512 + n]);
                lds[rl * 128 + nl] = f2h(v);
            }
        }
    __builtin_amdgcn_s_barrier();
    asm volatile("" ::: "memory");
#pragma unroll
    for (int it = 0; it < 4; ++it) {
        int idx = it * 512 + t;
        int row = idx >> 4, ch = idx & 15;
        *(half8*)&outh[(size_t)(m0 + row) * 512 + n0 + ch * 8] =
            *(const half8*)&lds[row * 128 + ch * 8];
    }
}

// ---------- chunk T ----------
__global__ __launch_bounds__(256) void chunk_t(
    const u16* __restrict__ QKVGh, u16* __restrict__ Tst)
{
    __shared__ u16 kth[64 * 144];
    __shared__ u16 vth[64 * 144];
    int t = threadIdx.x;
    int wid = t >> 6, lane = t & 63, quad = lane >> 4, l15 = lane & 15;
    int bh = blockIdx.x >> 3, c = blockIdx.x & 7;
    int b = bh >> 3, h = bh & 7;
    float gamma = 1.f - exp2f(-(float)(5 + h));
    float l2g = log2f(gamma);

    for (int cc = t; cc < 2048; cc += 256) {
        int d = cc & 63, mseg = cc >> 6;
        size_t gbase = (size_t)(b * 1024 + c * 128 + mseg * 4) * 2048 + h * 64 + d;
        us4 k4, v4;
#pragma unroll
        for (int i = 0; i < 4; ++i) {
            float kv = h2f(QKVGh[gbase + 512 + (size_t)i * 2048]);
            k4[i] = f2h(kv * exp2f((float)(127 - (mseg * 4 + i)) * l2g));
            v4[i] = QKVGh[gbase + 1024 + (size_t)i * 2048];
        }
        int base = d * 144 + (((mseg >> 1) + d) & 15) * 8 + (mseg & 1) * 4;
        *(us4*)&kth[base] = k4;
        *(us4*)&vth[base] = v4;
    }
    __syncthreads();
    f32x4 T[4];
#pragma unroll
    for (int dt = 0; dt < 4; ++dt) T[dt] = (f32x4){0.f, 0.f, 0.f, 0.f};
    int ra = wid * 16 + l15;
#pragma unroll
    for (int ks = 0; ks < 4; ++ks) {
        half8 av = *(const half8*)&vth[ra * 144 + ((ks * 4 + quad + ra) & 15) * 8];
#pragma unroll
        for (int dt = 0; dt < 4; ++dt) {
            int rb = dt * 16 + l15;
            half8 bk = *(const half8*)&kth[rb * 144 + ((ks * 4 + quad + rb) & 15) * 8];
            T[dt] = __builtin_amdgcn_mfma_f32_16x16x32_f16(av, bk, T[dt], 0, 0, 0);
        }
    }
#pragma unroll
    for (int dt = 0; dt < 4; ++dt)
#pragma unroll
        for (int r = 0; r < 4; ++r) {
            int i = wid * 16 + quad * 4 + r;
            int j = dt * 16 + l15;
            Tst[(((size_t)bh * 8 + c) * 64 + i) * 64 + j] = f2h(T[dt][r]);
        }
}

// ---------- tscan: per-(bh) prefix scan over chunk T's ----------
__global__ __launch_bounds__(256) void tscan(
    const u16* __restrict__ Tst, u16* __restrict__ Sst)
{
    int bh = blockIdx.x >> 3, p = blockIdx.x & 7;
    int h = bh & 7;
    float gamma = 1.f - exp2f(-(float)(5 + h));
    float g128 = exp2f(128.f * log2f(gamma));
    int e = p * 512 + threadIdx.x * 2;
    const u16* tp = Tst + (size_t)bh * 32768 + e;
    u16* sp = Sst + (size_t)bh * 32768 + e;
    float s0 = 0.f, s1 = 0.f;
#pragma unroll
    for (int c = 0; c < 8; ++c) {
        sp[c * 4096] = f2h(s0);
        sp[c * 4096 + 1] = f2h(s1);
        s0 = g128 * s0 + h2f(tp[c * 4096]);
        s1 = g128 * s1 + h2f(tp[c * 4096 + 1]);
    }
}

// ---------- retention: 8 waves (wave = 16 q-rows), prefix from Sst ----------
__global__ __launch_bounds__(512, 2) void retention_f16(
    const u16* __restrict__ QKVGh, const u16* __restrict__ Sst, u16* __restrict__ Zh)
{
    __shared__ u16 kh[128 * 64];     // 16 KB
    __shared__ u16 vth[64 * 144];    // 18 KB
    __shared__ u16 ph[8][16 * 132];  // 33 KB (per-wave P buffers)

    int t = threadIdx.x;
    int wid = t >> 6, lane = t & 63, quad = lane >> 4, l15 = lane & 15;
    int bh = blockIdx.x >> 3, qt = blockIdx.x & 7;
    int b = bh >> 3, h = bh & 7;
    int n0 = qt * 128;

    float gamma = 1.f - exp2f(-(float)(5 + h));
    float l2g = log2f(gamma);

    // K staging: 8 waves x 8 rows per iter = 64 rows; 2 iters for 128 rows
    {
        int srow = wid * 8 + (lane >> 3);
        int scol = (lane & 7) * 8;
#pragma unroll
        for (int i = 0; i < 2; ++i) {
            int r = i * 64 + srow;
            gl_lds16(&QKVGh[(size_t)(b * 1024 + n0 + r) * 2048 + 512 + h * 64 + scol],
                     &kh[(i * 64 + wid * 8) * 64]);
        }
    }
    for (int c = t; c < 2048; c += 512) {
        int d = c & 63, mseg = c >> 6;
        size_t gbase = (size_t)(b * 1024 + n0 + mseg * 4) * 2048 + 1024 + h * 64 + d;
        us4 v4 = {QKVGh[gbase], QKVGh[gbase + 2048],
                  QKVGh[gbase + 4096], QKVGh[gbase + 6144]};
        int base = d * 144 + (((mseg >> 1) + d) & 15) * 8 + (mseg & 1) * 4;
        *(us4*)&vth[base] = v4;
    }

    // Q fragments for this wave's 16 rows
    half8 aH[2], aHs[2];
    {
        int rowloc = wid * 16 + l15;
        int qrow = b * 1024 + n0 + rowloc;
        const u16* qp = QKVGh + (size_t)qrow * 2048 + h * 64;
        float qs = exp2f((float)(rowloc + 1) * l2g - 3.f);
#pragma unroll
        for (int ks = 0; ks < 2; ++ks) {
            aH[ks] = *(const half8*)&qp[ks * 32 + quad * 8];
#pragma unroll
            for (int j = 0; j < 8; ++j)
                aHs[ks][j] = (_Float16)((float)aH[ks][j] * qs);
        }
    }

    // prefix state
    half8 sf[2][4];
    {
        const u16* sp = &Sst[((size_t)bh * 8 + qt) * 4096];
#pragma unroll
        for (int ks = 0; ks < 2; ++ks)
#pragma unroll
            for (int dt = 0; dt < 4; ++dt)
                sf[ks][dt] = *(const half8*)&sp[(dt * 16 + l15) * 64 + ks * 32 + quad * 8];
    }
    __syncthreads();

    f32x4 yacc[4];
#pragma unroll
    for (int dt = 0; dt < 4; ++dt) yacc[dt] = (f32x4){0.f, 0.f, 0.f, 0.f};

#pragma unroll
    for (int ks = 0; ks < 2; ++ks)
#pragma unroll
        for (int dt = 0; dt < 4; ++dt)
            yacc[dt] = __builtin_amdgcn_mfma_f32_16x16x32_f16(aHs[ks], sf[ks][dt], yacc[dt], 0, 0, 0);

    // intra-chunk scores
    f32x4 sacc[8];
#pragma unroll
    for (int tn = 0; tn < 8; ++tn) sacc[tn] = (f32x4){0.f, 0.f, 0.f, 0.f};
#pragma unroll
    for (int tn = 0; tn < 8; ++tn)
#pragma unroll
        for (int ks = 0; ks < 2; ++ks) {
            half8 bH = *(const half8*)&kh[(tn * 16 + l15) * 64 + ks * 32 + quad * 8];
            sacc[tn] = __builtin_amdgcn_mfma_f32_16x16x32_f16(aH[ks], bH, sacc[tn], 0, 0, 0);
        }
#pragma unroll
    for (int tn = 0; tn < 8; ++tn) {
        int mloc = tn * 16 + l15;
#pragma unroll
        for (int r = 0; r < 4; ++r) {
            int nloc = wid * 16 + quad * 4 + r;
            int diff = nloc - mloc;
            float p = (diff >= 0) ? sacc[tn][r] * exp2f((float)diff * l2g - 3.0f) : 0.f;
            ph[wid][(quad * 4 + r) * 132 + tn * 16 + l15] = f2h(p);
        }
    }
    half8 pH[4];
#pragma unroll
    for (int ks = 0; ks < 4; ++ks)
        pH[ks] = *(const half8*)&ph[wid][l15 * 132 + ks * 32 + quad * 8];
#pragma unroll
    for (int dt = 0; dt < 4; ++dt) {
        int d = dt * 16 + l15;
#pragma unroll
        for (int ks = 0; ks < 4; ++ks) {
            half8 vv = *(const half8*)&vth[d * 144 + ((ks * 4 + quad + d) & 15) * 8];
            yacc[dt] = __builtin_amdgcn_mfma_f32_16x16x32_f16(pH[ks], vv, yacc[dt], 0, 0, 0);
        }
    }

    // groupnorm + swish gate + store
#pragma unroll
    for (int r = 0; r < 4; ++r) {
        float s1 = yacc[0][r] + yacc[1][r] + yacc[2][r] + yacc[3][r];
        float s2 = yacc[0][r] * yacc[0][r] + yacc[1][r] * yacc[1][r] +
                   yacc[2][r] * yacc[2][r] + yacc[3][r] * yacc[3][r];
#pragma unroll
        for (int o = 1; o <= 8; o <<= 1) {
            s1 += __shfl_xor(s1, o, 64);
            s2 += __shfl_xor(s2, o, 64);
        }
        float mu = s1 * (1.f / 64.f);
        float var = fmaxf(s2 * (1.f / 64.f) - mu * mu, 0.f);
        float rs = 1.f / sqrtf(var + 1e-5f);
        int nglob = n0 + wid * 16 + quad * 4 + r;
        size_t grow = (size_t)(b * 1024 + nglob);
#pragma unroll
        for (int dt = 0; dt < 4; ++dt) {
            int d = dt * 16 + l15;
            float yv = (yacc[dt][r] - mu) * rs;
            float gt = h2f(QKVGh[grow * 2048 + 1536 + h * 64 + d]);
            float sw = gt / (1.f + expf(-gt));
            Zh[grow * 512 + h * 64 + d] = f2h(yv * sw);
        }
    }
}

// ---------- final reduce ----------
__global__ __launch_bounds__(256) void fc_final(const float* __restrict__ fcpart,
                                                const float* __restrict__ fcb,
                                                float* __restrict__ out)
{
    __shared__ float red[4];
    int b = blockIdx.x, t = threadIdx.x;
    float4 v = *(const float4*)&fcpart[(size_t)b * 1024 + t * 4];
    float s = v.x + v.y + v.z + v.w;
    int wid = t >> 6, lane = t & 63;
#pragma unroll
    for (int o = 32; o >= 1; o >>= 1) s += __shfl_xor(s, o, 64);
    if (lane == 0) red[wid] = s;
    __syncthreads();
    if (t == 0) {
        float l = red[0] + red[1] + red[2] + red[3] + fcb[0];
        out[b] = 1.f / (1.f + expf(-l));
    }
}

extern "C" void kernel_launch(void* const* d_in, const int* in_sizes, int n_in,
                              void* d_out, int out_size, void* d_ws, size_t ws_size,
                              hipStream_t stream)
{
    const int* ids = (const int*)d_in[0];
    const float* emb = (const float*)d_in[1];
    const float* pos = (const float*)d_in[2];
    const float* ln_g = (const float*)d_in[3];
    const float* ln_b = (const float*)d_in[4];
    const float* Wq = (const float*)d_in[5];
    const float* Wk = (const float*)d_in[6];
    const float* Wv = (const float*)d_in[7];
    const float* Wg = (const float*)d_in[8];
    const float* Wo = (const float*)d_in[9];
    const float* W1 = (const float*)d_in[10];
    const float* b1 = (const float*)d_in[11];
    const float* W2 = (const float*)d_in[12];
    const float* b2 = (const float*)d_in[13];
    const float* fcW = (const float*)d_in[14];
    const float* fcb = (const float*)d_in[15];
    float* out = (float*)d_out;

    char* ws = (char*)d_ws;
    u16* WT     = (u16*)(ws);                  //  3,670,016
    u16* x0h    = (u16*)(ws + 3670016);        //  8,388,608  LN(emb) f16 (A + residual)
    u16* Zh     = (u16*)(ws + 12058624);       //  8,388,608  retention out f16
    u16* QKVGh  = (u16*)(ws + 20447232);       // 33,554,432  [8192][2048] f16
    float* fcpart = (float*)(ws + 54001664);   // 32,768
    u16* Tst    = (u16*)(ws + 54034432);       //  4,194,304  per-chunk T
    u16* Sst    = (u16*)(ws + 58228736);       //  4,194,304  prefix states
    u16* X1h = QKVGh;
    u16* Th  = (u16*)((char*)QKVGh + 8388608);
    u16* Hh  = (u16*)((char*)QKVGh + 16777216);
    u16* X2h = Zh;

    prep_kernel<<<1472, 256, 0, stream>>>(Wq, Wk, Wv, Wg, Wo, W1, W2, WT,
                                          ids, emb, pos, ln_g, ln_b, x0h);
    gemm_f16<<<256, 512, 0, stream>>>(x0h, WT, QKVGh, 2048);
    chunk_t<<<512, 256, 0, stream>>>(QKVGh, Tst);
    tscan<<<512, 256, 0, stream>>>(Tst, Sst);
    retention_f16<<<512, 512, 0, stream>>>(QKVGh, Sst, Zh);
    gemm_f16_n64<<<256, 512, 0, stream>>>(Zh, WT + 4 * 262144, X1h, x0h, nullptr, 1);
    ln_kernel<<<2048, 256, 0, stream>>>(X1h, ln_g, ln_b, Th, nullptr, nullptr);
    gemm_f16_n64<<<256, 512, 0, stream>>>(Th, WT + 5 * 262144, Hh, nullptr, b1, 2);
    gemm_f16_n64<<<256, 512, 0, stream>>>(Hh, WT + 6 * 262144, X2h, X1h, b2, 3);
    ln_kernel<<<2048, 256, 0, stream>>>(X2h, ln_g, ln_b, nullptr, fcW, fcpart);
    fc_final<<<8, 256, 0, stream>>>(fcpart, fcb, out);
}